// Round 4
// baseline (1785.211 us; speedup 1.0000x reference)
//
#include <hip/hip_runtime.h>
#include <math.h>

#define NPTS 8192
#define KNN 20

static __device__ __forceinline__ unsigned long long umin64(unsigned long long a, unsigned long long b) {
    return a < b ? a : b;
}

// Monotonic mapping: float bits -> unsigned, order-preserving; key = (dist, index) in one u64.
static __device__ __forceinline__ unsigned long long pack_key(float d, int j) {
    unsigned int u = __float_as_uint(d);
    u = (u & 0x80000000u) ? ~u : (u | 0x80000000u);
    return (((unsigned long long)u) << 32) | (unsigned int)j;
}

// ---------------- row squared norms: bit-faithful replica of np.sum(x*x, -1) ----------------
// numpy pairwise_sum: n<8 -> sequential; n<=128 -> 8 stride-8 accumulators,
// tree-combine ((r0+r1)+(r2+r3))+((r4+r5)+(r6+r7)), sequential remainder.
// Multiply separate from add (NO fma) -> contraction disabled.
template<int C>
__global__ void rowsq_np_kernel(const float* __restrict__ X, int ld, float* __restrict__ x2) {
#pragma clang fp contract(off)
    int i = blockIdx.x * blockDim.x + threadIdx.x;
    if (i >= NPTS) return;
    const float* row = X + (long)i * ld;
    float res;
    if (C < 8) {
        res = 0.f;
        for (int c = 0; c < C; ++c) res += row[c] * row[c];
    } else {
        float r[8];
#pragma unroll
        for (int j = 0; j < 8; ++j) r[j] = row[j] * row[j];
        int p = 8;
        for (; p < C - (C % 8); p += 8)
#pragma unroll
            for (int j = 0; j < 8; ++j) r[j] += row[p + j] * row[p + j];
        res = ((r[0] + r[1]) + (r[2] + r[3])) + ((r[4] + r[5]) + (r[6] + r[7]));
        for (; p < C; ++p) res += row[p] * row[p];
    }
    x2[i] = res;
}

// ---------------- pairwise distance (fp32), row-chunked ----------------
// dist[i - i0base, j] = (x2[i] + x2[j]) - 2*dot(X[i],X[j])
// dot: single accumulator, ascending-k explicit fmaf chain == BLAS sgemm microkernel order.
template<int C>
__global__ __launch_bounds__(256) void dist_kernel(const float* __restrict__ X, int ld,
                                                   const float* __restrict__ x2,
                                                   float* __restrict__ dist, int i0base) {
    __shared__ float As[C][68];   // [c][i_local]
    __shared__ float Bs[C][68];
    const int tid = threadIdx.x;
    const int i0 = i0base + blockIdx.y * 64;
    const int j0 = blockIdx.x * 64;

    for (int t = tid; t < 64 * C; t += 256) {
        int r = t / C, c = t % C;
        As[c][r] = X[(long)(i0 + r) * ld + c];
        Bs[c][r] = X[(long)(j0 + r) * ld + c];
    }
    __syncthreads();

    const int ty = tid >> 4, tx = tid & 15;
    float acc[4][4];
#pragma unroll
    for (int a = 0; a < 4; ++a)
#pragma unroll
        for (int b = 0; b < 4; ++b) acc[a][b] = 0.f;

    for (int c = 0; c < C; ++c) {          // ascending k, one fma acc per element
        float4 a4 = *(const float4*)&As[c][ty * 4];
        float4 b4 = *(const float4*)&Bs[c][tx * 4];
        float av[4] = {a4.x, a4.y, a4.z, a4.w};
        float bv[4] = {b4.x, b4.y, b4.z, b4.w};
#pragma unroll
        for (int ii = 0; ii < 4; ++ii)
#pragma unroll
            for (int jj = 0; jj < 4; ++jj)
                acc[ii][jj] = fmaf(av[ii], bv[jj], acc[ii][jj]);
    }

    float xj[4];
#pragma unroll
    for (int jj = 0; jj < 4; ++jj) xj[jj] = x2[j0 + tx * 4 + jj];
#pragma unroll
    for (int ii = 0; ii < 4; ++ii) {
        int rloc = blockIdx.y * 64 + ty * 4 + ii;
        float xi = x2[i0 + ty * 4 + ii];
        float4 o;
        o.x = (xi + xj[0]) - 2.f * acc[ii][0];   // 2*acc exact; order matches numpy
        o.y = (xi + xj[1]) - 2.f * acc[ii][1];
        o.z = (xi + xj[2]) - 2.f * acc[ii][2];
        o.w = (xi + xj[3]) - 2.f * acc[ii][3];
        *(float4*)&dist[(long)rloc * NPTS + j0 + tx * 4] = o;
    }
}

// ---------------- exact top-K ascending by (dist, index), row-chunked ----------------
__global__ __launch_bounds__(256) void topk_kernel(const float* __restrict__ dist, int* __restrict__ idx_out,
                                                   int rowbase) {
    __shared__ float d[NPTS];
    __shared__ unsigned long long wmin[4];
    const int tid = threadIdx.x;
    const int row = rowbase + blockIdx.x;
    const float* drow = dist + (long)blockIdx.x * NPTS;

    for (int t = tid; t < NPTS; t += 256) d[t] = drow[t];
    __syncthreads();

    unsigned long long seg = ~0ull;
    for (int m = 0; m < NPTS / 256; ++m) {
        int j = tid + 256 * m;
        seg = umin64(seg, pack_key(d[j], j));
    }

    for (int it = 0; it < KNN; ++it) {
        unsigned long long k = seg;
#pragma unroll
        for (int off = 32; off >= 1; off >>= 1) {
            unsigned long long o = __shfl_down(k, (unsigned)off);
            k = umin64(k, o);
        }
        if ((tid & 63) == 0) wmin[tid >> 6] = k;
        __syncthreads();
        unsigned long long g = umin64(umin64(wmin[0], wmin[1]), umin64(wmin[2], wmin[3]));
        int j = (int)(unsigned int)(g & 0xFFFFFFFFull);
        if (tid == 0) idx_out[(long)row * KNN + it] = j;
        __syncthreads();   // wmin consumed by all before owner mutates d/seg
        if (tid == (j & 255)) {
            d[j] = __int_as_float(0x7F800000);   // +inf
            seg = ~0ull;
            for (int m = 0; m < NPTS / 256; ++m) {
                int jj = tid + 256 * m;
                seg = umin64(seg, pack_key(d[jj], jj));
            }
        }
    }
}

// ---------------- erosion edge-conv (fp32, order-free exact) ----------------
template<int F, int C>
__global__ void erode_kernel(const float* __restrict__ X, int ld, const int* __restrict__ idx,
                             const float* __restrict__ w, float* __restrict__ out, int ldo) {
    __shared__ int nidx[KNN];
    __shared__ float neigh[KNN * C];
    const int tid = threadIdx.x;
    const int row = blockIdx.x;
    if (tid < KNN) nidx[tid] = idx[row * KNN + tid];
    __syncthreads();
    for (int t = tid; t < KNN * C; t += blockDim.x) {
        int k = t / C, c = t % C;
        neigh[t] = X[(long)nidx[k] * ld + c];
    }
    __syncthreads();
    if (tid < F * C) {
        int f = tid / C, c = tid % C;
        float m = neigh[c] - w[f * KNN * C + c];
        for (int k = 1; k < KNN; ++k)
            m = fminf(m, neigh[k * C + c] - w[(f * KNN + k) * C + c]);
        out[(long)row * ldo + tid] = m;
    }
}

// ---------------- fp32 GEMM + bias (+ReLU): ascending-k fmaf chain == sgemm ----------------
template<int RELU>
__global__ __launch_bounds__(256) void gemm_kernel(const float* __restrict__ A, const float* __restrict__ B,
                                                   const float* __restrict__ bias, float* __restrict__ Cm,
                                                   int K, int N) {
    __shared__ float As[16][68];
    __shared__ float Bs[16][68];
    const int tid = threadIdx.x;
    const int i0 = blockIdx.y * 64, j0 = blockIdx.x * 64;
    const int ty = tid >> 4, tx = tid & 15;
    float acc[4][4];
#pragma unroll
    for (int a = 0; a < 4; ++a)
#pragma unroll
        for (int b = 0; b < 4; ++b) acc[a][b] = 0.f;

    for (int k0 = 0; k0 < K; k0 += 16) {
#pragma unroll
        for (int q = 0; q < 4; ++q) {
            int t = tid + 256 * q;
            int r = t >> 4, c = t & 15;
            As[c][r] = (k0 + c < K) ? A[(long)(i0 + r) * K + k0 + c] : 0.f;
            int n = t & 63, kk = t >> 6;
            Bs[kk][n] = (k0 + kk < K && j0 + n < N) ? B[(long)(k0 + kk) * N + j0 + n] : 0.f;
        }
        __syncthreads();
#pragma unroll
        for (int kk = 0; kk < 16; ++kk) {      // k strictly ascending across tiles; pads are fmaf(0,0,acc)
            float4 a4 = *(const float4*)&As[kk][ty * 4];
            float4 b4 = *(const float4*)&Bs[kk][tx * 4];
            float av[4] = {a4.x, a4.y, a4.z, a4.w};
            float bv[4] = {b4.x, b4.y, b4.z, b4.w};
#pragma unroll
            for (int ii = 0; ii < 4; ++ii)
#pragma unroll
                for (int jj = 0; jj < 4; ++jj)
                    acc[ii][jj] = fmaf(av[ii], bv[jj], acc[ii][jj]);
        }
        __syncthreads();
    }

#pragma unroll
    for (int ii = 0; ii < 4; ++ii) {
        int i = i0 + ty * 4 + ii;
#pragma unroll
        for (int jj = 0; jj < 4; ++jj) {
            int j = j0 + tx * 4 + jj;
            if (j < N) {
                float v = acc[ii][jj] + bias[j];
                if (RELU) v = fmaxf(v, 0.f);
                Cm[(long)i * N + j] = v;
            }
        }
    }
}

// ---------------- log_softmax over 40 cols, wave per row, in place ----------------
__global__ void logsoftmax_kernel(float* __restrict__ out) {
    const int lane = threadIdx.x & 63;
    const int wid = threadIdx.x >> 6;
    const int row = blockIdx.x * 4 + wid;
    float* o = out + (long)row * 40;
    float v = (lane < 40) ? o[lane] : -INFINITY;
    float m = v;
#pragma unroll
    for (int off = 1; off < 64; off <<= 1) m = fmaxf(m, __shfl_xor(m, off));
    float e = (lane < 40) ? expf(v - m) : 0.f;
    float s = e;
#pragma unroll
    for (int off = 1; off < 64; off <<= 1) s += __shfl_xor(s, off);
    float r = (v - m) - logf(s);
    if (lane < 40) o[lane] = r;
}

extern "C" void kernel_launch(void* const* d_in, const int* in_sizes, int n_in,
                              void* d_out, int out_size, void* d_ws, size_t ws_size,
                              hipStream_t stream) {
    (void)in_sizes; (void)n_in; (void)out_size;
    const float* x     = (const float*)d_in[0];
    const float* w1    = (const float*)d_in[1];
    const float* w2    = (const float*)d_in[2];
    const float* w3    = (const float*)d_in[3];
    const float* lin1w = (const float*)d_in[4];
    const float* lin1b = (const float*)d_in[5];
    const float* wa    = (const float*)d_in[6];
    const float* ba    = (const float*)d_in[7];
    const float* wb    = (const float*)d_in[8];
    const float* bb    = (const float*)d_in[9];
    const float* wo    = (const float*)d_in[10];
    const float* bo    = (const float*)d_in[11];
    float* outp = (float*)d_out;

    // ---- ws_size-adaptive layout ----
    char* ws = (char*)d_ws;
    size_t off = 0;
    auto take = [&](size_t bytes) { char* p = ws + off; off += (bytes + 255) & ~(size_t)255; return p; };
    float* x2  = (float*)take((size_t)NPTS * 4);
    int*   idx = (int*)  take((size_t)NPTS * KNN * 4);
    float* h0  = (float*)take((size_t)NPTS * 420 * 4);
    size_t rest = (ws_size > off) ? (ws_size - off) : 0;
    char*  scratch = ws + off;

    int cr = (int)(rest / ((size_t)NPTS * 4));   // fp32 dist chunk rows
    if (cr > NPTS) cr = NPTS;
    cr &= ~63;
    if (cr < 64) cr = 64;
    float* dist = (float*)scratch;

    int mr = (int)(rest / 5632);                 // fp32 MLP chunk rows
    if (mr > NPTS) mr = NPTS;
    mr &= ~63;
    if (mr < 64) mr = 64;

    dim3 b256(256);
    dim3 grow(NPTS);

    // ---- stage 1: knn(x, C=3) -> erode -> x1 = h0[:, 0:60]
    rowsq_np_kernel<3><<<dim3(32), b256, 0, stream>>>(x, 3, x2);
    for (int r0 = 0; r0 < NPTS; r0 += cr) {
        int rows = (NPTS - r0 < cr) ? (NPTS - r0) : cr;
        dist_kernel<3><<<dim3(128, rows / 64), b256, 0, stream>>>(x, 3, x2, dist, r0);
        topk_kernel<<<dim3(rows), b256, 0, stream>>>(dist, idx, r0);
    }
    erode_kernel<20, 3><<<grow, dim3(64), 0, stream>>>(x, 3, idx, w1, h0 + 0, 420);

    // ---- stage 2: knn(x1, C=60) -> erode -> x2f = h0[:, 60:180]
    rowsq_np_kernel<60><<<dim3(32), b256, 0, stream>>>(h0, 420, x2);
    for (int r0 = 0; r0 < NPTS; r0 += cr) {
        int rows = (NPTS - r0 < cr) ? (NPTS - r0) : cr;
        dist_kernel<60><<<dim3(128, rows / 64), b256, 0, stream>>>(h0, 420, x2, dist, r0);
        topk_kernel<<<dim3(rows), b256, 0, stream>>>(dist, idx, r0);
    }
    erode_kernel<2, 60><<<grow, dim3(128), 0, stream>>>(h0, 420, idx, w2, h0 + 60, 420);

    // ---- stage 3: knn(x2f, C=120) -> erode -> x3 = h0[:, 180:420]
    rowsq_np_kernel<120><<<dim3(32), b256, 0, stream>>>(h0 + 60, 420, x2);
    for (int r0 = 0; r0 < NPTS; r0 += cr) {
        int rows = (NPTS - r0 < cr) ? (NPTS - r0) : cr;
        dist_kernel<120><<<dim3(128, rows / 64), b256, 0, stream>>>(h0 + 60, 420, x2, dist, r0);
        topk_kernel<<<dim3(rows), b256, 0, stream>>>(dist, idx, r0);
    }
    erode_kernel<2, 120><<<grow, dim3(256), 0, stream>>>(h0 + 60, 420, idx, w3, h0 + 180, 420);

    // ---- MLP (row-chunked; h1|h2|h3 live in scratch)
    for (int r0 = 0; r0 < NPTS; r0 += mr) {
        int rows = (NPTS - r0 < mr) ? (NPTS - r0) : mr;
        float* h1c = (float*)scratch;
        float* h2c = h1c + (size_t)mr * 1024;
        float* h3c = h2c + (size_t)mr * 256;
        gemm_kernel<1><<<dim3(16, rows / 64), b256, 0, stream>>>(h0 + (long)r0 * 420, lin1w, lin1b, h1c, 420, 1024);
        gemm_kernel<1><<<dim3(4, rows / 64), b256, 0, stream>>>(h1c, wa, ba, h2c, 1024, 256);
        gemm_kernel<1><<<dim3(2, rows / 64), b256, 0, stream>>>(h2c, wb, bb, h3c, 256, 128);
        gemm_kernel<0><<<dim3(1, rows / 64), b256, 0, stream>>>(h3c, wo, bo, outp + (long)r0 * 40, 128, 40);
        logsoftmax_kernel<<<dim3(rows / 4), b256, 0, stream>>>(outp + (long)r0 * 40);
    }
}